// Round 1
// baseline (1914.328 us; speedup 1.0000x reference)
//
#include <hip/hip_runtime.h>
#include <math.h>

#define BATCH 4
#define SEQ   2048
#define EMBD  1024
#define NHEAD 16
#define HDIM  64
#define M_ROWS (BATCH*SEQ)   /* 8192 */
#define QKV_N  (3*EMBD)      /* 3072 */

// ---------------------------------------------------------------------------
// Kernel 1: qkv = x @ W_qkv + b_qkv, fused RoPE(q,k) + 1/8 scale on q,
// scattered to Q/K/V in [B, H, L, Dh] layout.
// 128x128 tile, BK=16, 256 threads, 8x8 acc per thread.
// ---------------------------------------------------------------------------
__global__ __launch_bounds__(256)
void qkv_rope_kernel(const float* __restrict__ X,
                     const float* __restrict__ W,
                     const float* __restrict__ bias,
                     float* __restrict__ Qo,
                     float* __restrict__ Ko,
                     float* __restrict__ Vo)
{
    __shared__ float As[16][128];   // [k][m]
    __shared__ float Bs[16][128];   // [k][n]
    const int tid = threadIdx.x;
    const int tx = tid & 15;
    const int ty = tid >> 4;
    const int m0 = blockIdx.y * 128;
    const int n0 = blockIdx.x * 128;

    float acc[8][8];
#pragma unroll
    for (int i = 0; i < 8; i++)
#pragma unroll
        for (int j = 0; j < 8; j++) acc[i][j] = 0.f;

    for (int k0 = 0; k0 < EMBD; k0 += 16) {
#pragma unroll
        for (int t = 0; t < 2; t++) {
            int slot = tid + t * 256;        // 0..511
            int row = slot >> 2;             // 0..127
            int kg  = slot & 3;              // 0..3 (x4 floats)
            float4 a = *(const float4*)&X[(size_t)(m0 + row) * EMBD + k0 + kg * 4];
            As[kg * 4 + 0][row] = a.x; As[kg * 4 + 1][row] = a.y;
            As[kg * 4 + 2][row] = a.z; As[kg * 4 + 3][row] = a.w;
        }
#pragma unroll
        for (int t = 0; t < 2; t++) {
            int slot = tid + t * 256;        // 0..511
            int row = slot >> 5;             // 0..15
            int cg  = slot & 31;             // 0..31 (x4 floats)
            *(float4*)&Bs[row][cg * 4] =
                *(const float4*)&W[(size_t)(k0 + row) * QKV_N + n0 + cg * 4];
        }
        __syncthreads();
#pragma unroll
        for (int kk = 0; kk < 16; kk++) {
            float a[8], b[8];
            *(float4*)&a[0] = *(const float4*)&As[kk][ty * 8];
            *(float4*)&a[4] = *(const float4*)&As[kk][ty * 8 + 4];
            *(float4*)&b[0] = *(const float4*)&Bs[kk][tx * 8];
            *(float4*)&b[4] = *(const float4*)&Bs[kk][tx * 8 + 4];
#pragma unroll
            for (int i = 0; i < 8; i++)
#pragma unroll
                for (int j = 0; j < 8; j++)
                    acc[i][j] = fmaf(a[i], b[j], acc[i][j]);
        }
        __syncthreads();
    }

    // Epilogue: bias + RoPE + scatter. Block's 128 cols lie in one section.
    const int n_base = n0 + tx * 8;
    const int sec  = n_base / EMBD;          // 0=q 1=k 2=v
    const int dcol = n_base - sec * EMBD;    // 0..1023
    const int h    = dcol >> 6;
    const int dh0  = dcol & 63;              // even

    float invf[4];
#pragma unroll
    for (int p = 0; p < 4; p++)
        invf[p] = powf(10000.0f, -((float)(dh0 + 2 * p)) * (1.0f / 64.0f));

    float bj[8];
#pragma unroll
    for (int j = 0; j < 8; j++) bj[j] = bias[n_base + j];

#pragma unroll
    for (int i = 0; i < 8; i++) {
        int m = m0 + ty * 8 + i;
        int b = m >> 11;       // /2048
        int l = m & 2047;
        size_t base = (((size_t)b * NHEAD + h) * SEQ + l) * HDIM + dh0;
        if (sec == 2) {
            float4 v0 = { acc[i][0] + bj[0], acc[i][1] + bj[1],
                          acc[i][2] + bj[2], acc[i][3] + bj[3] };
            float4 v1 = { acc[i][4] + bj[4], acc[i][5] + bj[5],
                          acc[i][6] + bj[6], acc[i][7] + bj[7] };
            *(float4*)&Vo[base]     = v0;
            *(float4*)&Vo[base + 4] = v1;
        } else {
            float* op = (sec == 0) ? Qo : Ko;
            const float qs = (sec == 0) ? 0.125f : 1.0f;  // fold 1/sqrt(64) into Q
            float outv[8];
#pragma unroll
            for (int p = 0; p < 4; p++) {
                float x1 = acc[i][2 * p]     + bj[2 * p];
                float x2 = acc[i][2 * p + 1] + bj[2 * p + 1];
                float sv, cv;
                sincosf((float)l * invf[p], &sv, &cv);
                outv[2 * p]     = (x1 * cv - x2 * sv) * qs;
                outv[2 * p + 1] = (x1 * sv + x2 * cv) * qs;
            }
            *(float4*)&op[base]     = *(float4*)&outv[0];
            *(float4*)&op[base + 4] = *(float4*)&outv[4];
        }
    }
}

// ---------------------------------------------------------------------------
// Kernel 2: causal flash attention, fp32. One query per thread, 128 q/block.
// K/V tiles of 64 keys staged in LDS (broadcast reads). Online softmax in
// 16-key chunks. Output written to [B, L, H*Dh] for the proj GEMM.
// ---------------------------------------------------------------------------
__global__ __launch_bounds__(128)
void attn_kernel(const float* __restrict__ Q, const float* __restrict__ K,
                 const float* __restrict__ V, const int* __restrict__ amask,
                 float* __restrict__ O)
{
    __shared__ float Ks[64][64];
    __shared__ float Vs[64][64];
    __shared__ int   Ms[64];

    const int bh = blockIdx.x;               // 0..63
    const int b  = bh >> 4;
    // heavy (late-q) blocks first for better load balance
    const int q0 = ((int)gridDim.y - 1 - (int)blockIdx.y) * 128;
    const int tid = threadIdx.x;             // 0..127
    const int q   = q0 + tid;

    const float* Qrow = &Q[(((size_t)bh) * SEQ + q) * HDIM];
    float4 qr[16];
#pragma unroll
    for (int i = 0; i < 16; i++) qr[i] = *(const float4*)&Qrow[i * 4];

    float o[64];
#pragma unroll
    for (int i = 0; i < 64; i++) o[i] = 0.f;
    float mrun = -INFINITY, lrun = 0.f;

    const float* Kbase = &K[((size_t)bh) * SEQ * HDIM];
    const float* Vbase = &V[((size_t)bh) * SEQ * HDIM];
    const int ntiles = q0 / 64 + 2;          // kt*64 <= q0+127

    for (int kt = 0; kt < ntiles; kt++) {
        const float* Kg = Kbase + (size_t)kt * 64 * HDIM;
        const float* Vg = Vbase + (size_t)kt * 64 * HDIM;
#pragma unroll
        for (int t = 0; t < 8; t++) {
            int slot = tid + t * 128;        // 0..1023 float4 slots
            int r = slot >> 4;
            int c = (slot & 15) * 4;
            *(float4*)&Ks[r][c] = *(const float4*)&Kg[slot * 4];
            *(float4*)&Vs[r][c] = *(const float4*)&Vg[slot * 4];
        }
        if (tid < 64) Ms[tid] = amask[b * SEQ + kt * 64 + tid];
        __syncthreads();

        for (int ch = 0; ch < 4; ch++) {
            float s[16];
#pragma unroll
            for (int jj = 0; jj < 16; jj++) {
                int jl = ch * 16 + jj;
                int jg = kt * 64 + jl;
                float sv = 0.f;
#pragma unroll
                for (int d4 = 0; d4 < 16; d4++) {
                    float4 kv = *(const float4*)&Ks[jl][d4 * 4];
                    sv = fmaf(qr[d4].x, kv.x, sv);
                    sv = fmaf(qr[d4].y, kv.y, sv);
                    sv = fmaf(qr[d4].z, kv.z, sv);
                    sv = fmaf(qr[d4].w, kv.w, sv);
                }
                if (jg > q || Ms[jl] == 0) sv = -INFINITY;
                s[jj] = sv;
            }
            float cmax = s[0];
#pragma unroll
            for (int jj = 1; jj < 16; jj++) cmax = fmaxf(cmax, s[jj]);
            if (cmax == -INFINITY) continue;   // fully-masked chunk (above diag)

            float mnew  = fmaxf(mrun, cmax);
            float scale = expf(mrun - mnew);   // exp(-inf)=0 handles first chunk
            lrun *= scale;
#pragma unroll
            for (int d = 0; d < 64; d++) o[d] *= scale;
#pragma unroll
            for (int jj = 0; jj < 16; jj++) {
                int jl = ch * 16 + jj;
                float p = expf(s[jj] - mnew);
                lrun += p;
#pragma unroll
                for (int d4 = 0; d4 < 16; d4++) {
                    float4 vv = *(const float4*)&Vs[jl][d4 * 4];
                    o[d4 * 4 + 0] = fmaf(p, vv.x, o[d4 * 4 + 0]);
                    o[d4 * 4 + 1] = fmaf(p, vv.y, o[d4 * 4 + 1]);
                    o[d4 * 4 + 2] = fmaf(p, vv.z, o[d4 * 4 + 2]);
                    o[d4 * 4 + 3] = fmaf(p, vv.w, o[d4 * 4 + 3]);
                }
            }
            mrun = mnew;
        }
        __syncthreads();
    }

    const int h = bh & 15;
    float inv_l = 1.0f / lrun;
    float* Op = &O[(((size_t)b * SEQ + q) * EMBD) + h * HDIM];
#pragma unroll
    for (int d4 = 0; d4 < 16; d4++) {
        float4 ov = { o[d4 * 4 + 0] * inv_l, o[d4 * 4 + 1] * inv_l,
                      o[d4 * 4 + 2] * inv_l, o[d4 * 4 + 3] * inv_l };
        *(float4*)&Op[d4 * 4] = ov;
    }
}

// ---------------------------------------------------------------------------
// Kernel 3: out = attn_out @ W_proj + b_proj.  Same tile scheme as kernel 1.
// ---------------------------------------------------------------------------
__global__ __launch_bounds__(256)
void proj_kernel(const float* __restrict__ X,
                 const float* __restrict__ W,
                 const float* __restrict__ bias,
                 float* __restrict__ out)
{
    __shared__ float As[16][128];
    __shared__ float Bs[16][128];
    const int tid = threadIdx.x;
    const int tx = tid & 15;
    const int ty = tid >> 4;
    const int m0 = blockIdx.y * 128;
    const int n0 = blockIdx.x * 128;

    float acc[8][8];
#pragma unroll
    for (int i = 0; i < 8; i++)
#pragma unroll
        for (int j = 0; j < 8; j++) acc[i][j] = 0.f;

    for (int k0 = 0; k0 < EMBD; k0 += 16) {
#pragma unroll
        for (int t = 0; t < 2; t++) {
            int slot = tid + t * 256;
            int row = slot >> 2;
            int kg  = slot & 3;
            float4 a = *(const float4*)&X[(size_t)(m0 + row) * EMBD + k0 + kg * 4];
            As[kg * 4 + 0][row] = a.x; As[kg * 4 + 1][row] = a.y;
            As[kg * 4 + 2][row] = a.z; As[kg * 4 + 3][row] = a.w;
        }
#pragma unroll
        for (int t = 0; t < 2; t++) {
            int slot = tid + t * 256;
            int row = slot >> 5;
            int cg  = slot & 31;
            *(float4*)&Bs[row][cg * 4] =
                *(const float4*)&W[(size_t)(k0 + row) * EMBD + n0 + cg * 4];
        }
        __syncthreads();
#pragma unroll
        for (int kk = 0; kk < 16; kk++) {
            float a[8], b[8];
            *(float4*)&a[0] = *(const float4*)&As[kk][ty * 8];
            *(float4*)&a[4] = *(const float4*)&As[kk][ty * 8 + 4];
            *(float4*)&b[0] = *(const float4*)&Bs[kk][tx * 8];
            *(float4*)&b[4] = *(const float4*)&Bs[kk][tx * 8 + 4];
#pragma unroll
            for (int i = 0; i < 8; i++)
#pragma unroll
                for (int j = 0; j < 8; j++)
                    acc[i][j] = fmaf(a[i], b[j], acc[i][j]);
        }
        __syncthreads();
    }

    const int n_base = n0 + tx * 8;
    float bj[8];
#pragma unroll
    for (int j = 0; j < 8; j++) bj[j] = bias[n_base + j];
#pragma unroll
    for (int i = 0; i < 8; i++) {
        int m = m0 + ty * 8 + i;
        float4 v0 = { acc[i][0] + bj[0], acc[i][1] + bj[1],
                      acc[i][2] + bj[2], acc[i][3] + bj[3] };
        float4 v1 = { acc[i][4] + bj[4], acc[i][5] + bj[5],
                      acc[i][6] + bj[6], acc[i][7] + bj[7] };
        *(float4*)&out[(size_t)m * EMBD + n_base]     = v0;
        *(float4*)&out[(size_t)m * EMBD + n_base + 4] = v1;
    }
}

// ---------------------------------------------------------------------------
extern "C" void kernel_launch(void* const* d_in, const int* in_sizes, int n_in,
                              void* d_out, int out_size, void* d_ws, size_t ws_size,
                              hipStream_t stream)
{
    const float* x     = (const float*)d_in[0];
    const float* Wqkv  = (const float*)d_in[1];
    const float* bqkv  = (const float*)d_in[2];
    const float* Wproj = (const float*)d_in[3];
    const float* bproj = (const float*)d_in[4];
    const int*   amask = (const int*)d_in[5];
    float* out = (float*)d_out;

    const size_t elems = (size_t)BATCH * NHEAD * SEQ * HDIM;  // 8,388,608
    float* Qw = (float*)d_ws;
    float* Kw = Qw + elems;
    float* Vw = Kw + elems;
    float* Ow = Vw + elems;   // [B, L, D] for proj; total ws use = 128 MiB

    qkv_rope_kernel<<<dim3(QKV_N / 128, M_ROWS / 128), 256, 0, stream>>>(
        x, Wqkv, bqkv, Qw, Kw, Vw);
    attn_kernel<<<dim3(BATCH * NHEAD, SEQ / 128), 128, 0, stream>>>(
        Qw, Kw, Vw, amask, Ow);
    proj_kernel<<<dim3(EMBD / 128, M_ROWS / 128), 256, 0, stream>>>(
        Ow, Wproj, bproj, out);
}

// Round 2
// 477.713 us; speedup vs baseline: 4.0073x; 4.0073x over previous
//
#include <hip/hip_runtime.h>
#include <math.h>

typedef __bf16 bf16_t;
typedef __bf16 bf16x8 __attribute__((ext_vector_type(8)));
typedef float f32x4 __attribute__((ext_vector_type(4)));
typedef unsigned short u16;
typedef unsigned short u16x8 __attribute__((ext_vector_type(8)));
typedef unsigned short u16x4 __attribute__((ext_vector_type(4)));

#define BATCH 4
#define SEQ   2048
#define EMBD  1024
#define NHEAD 16
#define HDIM  64
#define MROWS 8192
#define QKVN  3072

__device__ __forceinline__ u16 f2bf(float f) {
    union { float f; unsigned u; } cv; cv.f = f;
    unsigned u = cv.u;
    return (u16)((u + 0x7FFFu + ((u >> 16) & 1u)) >> 16);
}

__device__ __forceinline__ void glds16(const void* g, void* l) {
    __builtin_amdgcn_global_load_lds(
        (const __attribute__((address_space(1))) unsigned int*)(g),
        (__attribute__((address_space(3))) unsigned int*)(l), 16, 0, 0);
}

// ---------------------------------------------------------------------------
// fp32 -> bf16 elementwise convert (4 elems/thread)
// ---------------------------------------------------------------------------
__global__ __launch_bounds__(256)
void convert_f32_bf16(const float* __restrict__ in, u16* __restrict__ out, int n4) {
    int i = blockIdx.x * 256 + threadIdx.x;
    if (i < n4) {
        float4 v = ((const float4*)in)[i];
        u16x4 o = { f2bf(v.x), f2bf(v.y), f2bf(v.z), f2bf(v.w) };
        ((u16x4*)out)[i] = o;
    }
}

// ---------------------------------------------------------------------------
// W [K][N] fp32 -> Wt [N][K] bf16 (64x64 tiles via LDS)
// ---------------------------------------------------------------------------
__global__ __launch_bounds__(256)
void transpose_convert(const float* __restrict__ W, u16* __restrict__ Wt, int K, int N) {
    __shared__ u16 T[64][68];
    const int tx = threadIdx.x & 15, ty = threadIdx.x >> 4;
    const int n0 = blockIdx.x * 64, k0 = blockIdx.y * 64;
#pragma unroll
    for (int r = 0; r < 4; r++) {
        int k = k0 + ty + r * 16;
        float4 w = *(const float4*)&W[(size_t)k * N + n0 + tx * 4];
        T[tx * 4 + 0][ty + r * 16] = f2bf(w.x);
        T[tx * 4 + 1][ty + r * 16] = f2bf(w.y);
        T[tx * 4 + 2][ty + r * 16] = f2bf(w.z);
        T[tx * 4 + 3][ty + r * 16] = f2bf(w.w);
    }
    __syncthreads();
#pragma unroll
    for (int r = 0; r < 4; r++) {
        int nl = ty + r * 16;
        u16x4 v = { T[nl][tx * 4 + 0], T[nl][tx * 4 + 1],
                    T[nl][tx * 4 + 2], T[nl][tx * 4 + 3] };
        *(u16x4*)&Wt[(size_t)(n0 + nl) * K + k0 + tx * 4] = v;
    }
}

// ---------------------------------------------------------------------------
// qkv = Xb @ Wt^T + b, fused RoPE + 0.125 scale on Q, scatter [B,H,L,Dh] bf16.
// m97-structure: 128x128 tile, BK=32, global_load_lds(16B), 16 MFMA/wave/iter.
// ---------------------------------------------------------------------------
__global__ __launch_bounds__(256)
void qkv_gemm(const u16* __restrict__ A, const u16* __restrict__ Bt,
              const float* __restrict__ bias,
              u16* __restrict__ Qo, u16* __restrict__ Ko, u16* __restrict__ Vo) {
    __shared__ u16 As[128 * 32];
    __shared__ u16 Bs[128 * 32];
    const int tid = threadIdx.x;
    const int wv = tid >> 6, ln = tid & 63;
    const int quad = ln >> 4, l16 = ln & 15;
    const int m0 = blockIdx.y * 128, n0 = blockIdx.x * 128;
    const int wm = wv >> 1, wn = wv & 1;

    f32x4 acc[4][4] = {};
    for (int k0 = 0; k0 < EMBD; k0 += 32) {
#pragma unroll
        for (int p = 0; p < 2; p++) {
            int slot = p * 256 + tid;
            int row = slot >> 2, ch = slot & 3;
            glds16(A  + (size_t)(m0 + row) * EMBD + k0 + ch * 8, As + (p * 256 + wv * 64) * 8);
            glds16(Bt + (size_t)(n0 + row) * EMBD + k0 + ch * 8, Bs + (p * 256 + wv * 64) * 8);
        }
        __syncthreads();
        bf16x8 af[4], bfr[4];
#pragma unroll
        for (int i = 0; i < 4; i++) af[i]  = *(const bf16x8*)&As[(wm * 64 + i * 16 + l16) * 32 + quad * 8];
#pragma unroll
        for (int j = 0; j < 4; j++) bfr[j] = *(const bf16x8*)&Bs[(wn * 64 + j * 16 + l16) * 32 + quad * 8];
#pragma unroll
        for (int i = 0; i < 4; i++)
#pragma unroll
            for (int j = 0; j < 4; j++)
                acc[i][j] = __builtin_amdgcn_mfma_f32_16x16x32_bf16(af[i], bfr[j], acc[i][j], 0, 0, 0);
        __syncthreads();
    }

    const int sec = n0 >> 10;   // whole block inside one of q/k/v (1024 % 128 == 0)
    if (sec == 2) {
#pragma unroll
        for (int i = 0; i < 4; i++)
#pragma unroll
            for (int r = 0; r < 4; r++) {
                int m = m0 + wm * 64 + i * 16 + quad * 4 + r;
                int b = m >> 11, l = m & 2047;
#pragma unroll
                for (int j = 0; j < 4; j++) {
                    int n = n0 + wn * 64 + j * 16 + l16;
                    int dcol = n & 1023;
                    int h = dcol >> 6, dh = dcol & 63;
                    float v = acc[i][j][r] + bias[n];
                    Vo[(((size_t)b * NHEAD + h) * SEQ + l) * HDIM + dh] = f2bf(v);
                }
            }
    } else {
        u16* O = (sec == 0) ? Qo : Ko;
        const float qs = (sec == 0) ? 0.125f : 1.0f;
        float invf[4];
#pragma unroll
        for (int j = 0; j < 4; j++) {
            int dh = (wn * 64 + j * 16 + l16) & 63;
            invf[j] = powf(10000.0f, -(float)(dh & 62) * (1.0f / 64.0f));
        }
#pragma unroll
        for (int i = 0; i < 4; i++)
#pragma unroll
            for (int r = 0; r < 4; r++) {
                int m = m0 + wm * 64 + i * 16 + quad * 4 + r;
                int b = m >> 11, l = m & 2047;
#pragma unroll
                for (int j = 0; j < 4; j++) {
                    int n = n0 + wn * 64 + j * 16 + l16;
                    int h = (n & 1023) >> 6, dh = n & 63;
                    float v = acc[i][j][r] + bias[n];
                    float p = __shfl_xor(v, 1, 64);   // RoPE partner (adjacent col)
                    float sv, cv;
                    __sincosf((float)l * invf[j], &sv, &cv);
                    float o = (l16 & 1) ? (p * sv + v * cv) : (v * cv - p * sv);
                    O[(((size_t)b * NHEAD + h) * SEQ + l) * HDIM + dh] = f2bf(o * qs);
                }
            }
    }
}

// ---------------------------------------------------------------------------
// Flash attention, bf16 MFMA. 4 waves x 32 q-rows, K-tile = 128.
// Ks XOR-swizzled; Vs transposed+swizzled; P via per-wave swizzled LDS.
// ---------------------------------------------------------------------------
__global__ __launch_bounds__(256)
void attn_mfma(const u16* __restrict__ Qb, const u16* __restrict__ Kb,
               const u16* __restrict__ Vb, const int* __restrict__ amask,
               u16* __restrict__ Ob) {
    __shared__ u16 Ks[128 * 64];        // 16 KB  [key][dh-chunk swz]
    __shared__ u16 Vs[64 * 128];        // 16 KB  [dh][key-chunk swz]
    __shared__ u16 Ps[4 * 32 * 128];    // 32 KB  per-wave [qrow][key-chunk swz]
    const int tid = threadIdx.x;
    const int wv = tid >> 6, ln = tid & 63;
    const int quad = ln >> 4, l16 = ln & 15;
    const int bx = blockIdx.x;
    const int qt = 15 - (bx >> 6);      // heavy q-tiles first
    const int bh = bx & 63;
    const int b = bh >> 4, h = bh & 15;
    const int q0 = qt * 128 + wv * 32;

    const u16* Qg = Qb + (size_t)bh * SEQ * HDIM;
    const u16* Kg = Kb + (size_t)bh * SEQ * HDIM;
    const u16* Vg = Vb + (size_t)bh * SEQ * HDIM;

    bf16x8 qf[2][2];
#pragma unroll
    for (int mi = 0; mi < 2; mi++)
#pragma unroll
        for (int ks = 0; ks < 2; ks++)
            qf[mi][ks] = *(const bf16x8*)&Qg[(size_t)(q0 + mi * 16 + l16) * HDIM + ks * 32 + quad * 8];

    f32x4 o[2][4] = {};
    float mrun[2][4], lrun[2][4];
#pragma unroll
    for (int mi = 0; mi < 2; mi++)
#pragma unroll
        for (int r = 0; r < 4; r++) { mrun[mi][r] = -1e30f; lrun[mi][r] = 0.f; }

    u16* Pw = Ps + wv * 32 * 128;

    for (int kt = 0; kt <= qt; kt++) {
        const int kbase = kt * 128;
        // --- stage K (swizzled 16B chunks) ---
#pragma unroll
        for (int p = 0; p < 4; p++) {
            int slot = p * 256 + tid;          // 0..1023
            int key = slot >> 3, ch = slot & 7;
            u16x8 kv = *(const u16x8*)&Kg[(size_t)(kbase + key) * HDIM + ch * 8];
            *(u16x8*)&Ks[key * 64 + ((ch ^ (key & 7)) * 8)] = kv;
        }
        // --- stage V transposed (Vs[dh][key], swizzled key-chunks) ---
        {
            int key = tid & 127, half = tid >> 7;
            int chn = key >> 3, kin = key & 7;
#pragma unroll
            for (int c = 0; c < 4; c++) {
                u16x8 vv = *(const u16x8*)&Vg[(size_t)(kbase + key) * HDIM + half * 32 + c * 8];
#pragma unroll
                for (int e = 0; e < 8; e++) {
                    int dh = half * 32 + c * 8 + e;
                    Vs[dh * 128 + ((chn ^ (dh & 7)) * 8) + kin] = vv[e];
                }
            }
        }
        __syncthreads();

        // --- S = Q K^T (per wave: 32 x 128) ---
        f32x4 s[2][8];
#pragma unroll
        for (int mi = 0; mi < 2; mi++)
#pragma unroll
            for (int nj = 0; nj < 8; nj++) {
                f32x4 a = {};
#pragma unroll
                for (int ks = 0; ks < 2; ks++) {
                    int key = nj * 16 + l16;
                    bf16x8 kf = *(const bf16x8*)&Ks[key * 64 + (((ks * 4 + quad) ^ (key & 7)) * 8)];
                    a = __builtin_amdgcn_mfma_f32_16x16x32_bf16(qf[mi][ks], kf, a, 0, 0, 0);
                }
                s[mi][nj] = a;
            }

        // --- masks ---
#pragma unroll
        for (int nj = 0; nj < 8; nj++) {
            int key = kbase + nj * 16 + l16;
            int mv = amask[b * SEQ + key];
#pragma unroll
            for (int mi = 0; mi < 2; mi++)
#pragma unroll
                for (int r = 0; r < 4; r++) {
                    int qrow = q0 + mi * 16 + quad * 4 + r;
                    if (mv == 0 || (kt == qt && key > qrow)) s[mi][nj][r] = -1e30f;
                }
        }

        // --- online softmax (rows live in 16-lane groups sharing quad) ---
#pragma unroll
        for (int mi = 0; mi < 2; mi++)
#pragma unroll
            for (int r = 0; r < 4; r++) {
                float rm = s[mi][0][r];
#pragma unroll
                for (int nj = 1; nj < 8; nj++) rm = fmaxf(rm, s[mi][nj][r]);
#pragma unroll
                for (int off = 1; off < 16; off <<= 1) rm = fmaxf(rm, __shfl_xor(rm, off, 64));
                float mnew = fmaxf(mrun[mi][r], rm);
                float alpha = __expf(mrun[mi][r] - mnew);
#pragma unroll
                for (int nd = 0; nd < 4; nd++) o[mi][nd][r] *= alpha;
                float rs = 0.f;
#pragma unroll
                for (int nj = 0; nj < 8; nj++) {
                    float pe = __expf(s[mi][nj][r] - mnew);
                    s[mi][nj][r] = pe;
                    rs += pe;
                }
#pragma unroll
                for (int off = 1; off < 16; off <<= 1) rs += __shfl_xor(rs, off, 64);
                lrun[mi][r] = lrun[mi][r] * alpha + rs;
                mrun[mi][r] = mnew;
            }

        // --- P: C-frag -> A-frag via per-wave LDS (bf16, swizzled) ---
#pragma unroll
        for (int mi = 0; mi < 2; mi++)
#pragma unroll
            for (int nj = 0; nj < 8; nj++)
#pragma unroll
                for (int r = 0; r < 4; r++) {
                    int row = mi * 16 + quad * 4 + r;
                    int col = nj * 16 + l16;
                    Pw[row * 128 + (((col >> 3) ^ (row & 7)) * 8) + (col & 7)] = f2bf(s[mi][nj][r]);
                }

        // --- O += P V ---
#pragma unroll
        for (int mi = 0; mi < 2; mi++)
#pragma unroll
            for (int nd = 0; nd < 4; nd++) {
                f32x4 a = o[mi][nd];
#pragma unroll
                for (int ks = 0; ks < 4; ks++) {
                    int m = mi * 16 + l16;
                    bf16x8 pf = *(const bf16x8*)&Pw[m * 128 + (((ks * 4 + quad) ^ (m & 7)) * 8)];
                    int dh = nd * 16 + l16;
                    bf16x8 vf = *(const bf16x8*)&Vs[dh * 128 + (((ks * 4 + quad) ^ (dh & 7)) * 8)];
                    a = __builtin_amdgcn_mfma_f32_16x16x32_bf16(pf, vf, a, 0, 0, 0);
                }
                o[mi][nd] = a;
            }
        __syncthreads();
    }

    // --- epilogue: normalize, write bf16 [B*L][EMBD] for proj GEMM ---
#pragma unroll
    for (int mi = 0; mi < 2; mi++)
#pragma unroll
        for (int r = 0; r < 4; r++) {
            float inv = 1.0f / lrun[mi][r];
            int q = q0 + mi * 16 + quad * 4 + r;
            size_t rowoff = ((size_t)b * SEQ + q) * EMBD + h * HDIM;
#pragma unroll
            for (int nd = 0; nd < 4; nd++)
                Ob[rowoff + nd * 16 + l16] = f2bf(o[mi][nd][r] * inv);
        }
}

// ---------------------------------------------------------------------------
// out = Ob @ Wprojt^T + b (fp32 out)
// ---------------------------------------------------------------------------
__global__ __launch_bounds__(256)
void proj_gemm(const u16* __restrict__ A, const u16* __restrict__ Bt,
               const float* __restrict__ bias, float* __restrict__ out) {
    __shared__ u16 As[128 * 32];
    __shared__ u16 Bs[128 * 32];
    const int tid = threadIdx.x;
    const int wv = tid >> 6, ln = tid & 63;
    const int quad = ln >> 4, l16 = ln & 15;
    const int m0 = blockIdx.y * 128, n0 = blockIdx.x * 128;
    const int wm = wv >> 1, wn = wv & 1;

    f32x4 acc[4][4] = {};
    for (int k0 = 0; k0 < EMBD; k0 += 32) {
#pragma unroll
        for (int p = 0; p < 2; p++) {
            int slot = p * 256 + tid;
            int row = slot >> 2, ch = slot & 3;
            glds16(A  + (size_t)(m0 + row) * EMBD + k0 + ch * 8, As + (p * 256 + wv * 64) * 8);
            glds16(Bt + (size_t)(n0 + row) * EMBD + k0 + ch * 8, Bs + (p * 256 + wv * 64) * 8);
        }
        __syncthreads();
        bf16x8 af[4], bfr[4];
#pragma unroll
        for (int i = 0; i < 4; i++) af[i]  = *(const bf16x8*)&As[(wm * 64 + i * 16 + l16) * 32 + quad * 8];
#pragma unroll
        for (int j = 0; j < 4; j++) bfr[j] = *(const bf16x8*)&Bs[(wn * 64 + j * 16 + l16) * 32 + quad * 8];
#pragma unroll
        for (int i = 0; i < 4; i++)
#pragma unroll
            for (int j = 0; j < 4; j++)
                acc[i][j] = __builtin_amdgcn_mfma_f32_16x16x32_bf16(af[i], bfr[j], acc[i][j], 0, 0, 0);
        __syncthreads();
    }
#pragma unroll
    for (int i = 0; i < 4; i++)
#pragma unroll
        for (int r = 0; r < 4; r++) {
            int m = m0 + wm * 64 + i * 16 + quad * 4 + r;
#pragma unroll
            for (int j = 0; j < 4; j++) {
                int n = n0 + wn * 64 + j * 16 + l16;
                out[(size_t)m * EMBD + n] = acc[i][j][r] + bias[n];
            }
        }
}

// ---------------------------------------------------------------------------
extern "C" void kernel_launch(void* const* d_in, const int* in_sizes, int n_in,
                              void* d_out, int out_size, void* d_ws, size_t ws_size,
                              hipStream_t stream)
{
    const float* x     = (const float*)d_in[0];
    const float* Wqkv  = (const float*)d_in[1];
    const float* bqkv  = (const float*)d_in[2];
    const float* Wproj = (const float*)d_in[3];
    const float* bproj = (const float*)d_in[4];
    const int*   amask = (const int*)d_in[5];
    float* out = (float*)d_out;

    char* ws = (char*)d_ws;
    u16* Xb     = (u16*)(ws);                    // 16.78 MB
    u16* Wqkvt  = (u16*)(ws + 16777216);         //  6.29 MB  [3072][1024]
    u16* Wprojt = (u16*)(ws + 23068672);         //  2.10 MB  [1024][1024]
    u16* Qb     = (u16*)(ws + 25165824);         // 16.78 MB  [B,H,L,Dh]
    u16* Kb     = (u16*)(ws + 41943040);
    u16* Vb     = (u16*)(ws + 58720256);
    u16* Ob     = (u16*)(ws + 75497472);         // 16.78 MB  [B*L][EMBD]

    convert_f32_bf16<<<8192, 256, 0, stream>>>(x, Xb, MROWS * EMBD / 4);
    transpose_convert<<<dim3(48, 16), 256, 0, stream>>>(Wqkv, Wqkvt, EMBD, QKVN);
    transpose_convert<<<dim3(16, 16), 256, 0, stream>>>(Wproj, Wprojt, EMBD, EMBD);
    qkv_gemm<<<dim3(QKVN / 128, MROWS / 128), 256, 0, stream>>>(Xb, Wqkvt, bqkv, Qb, Kb, Vb);
    attn_mfma<<<1024, 256, 0, stream>>>(Qb, Kb, Vb, amask, Ob);
    proj_gemm<<<dim3(EMBD / 128, MROWS / 128), 256, 0, stream>>>(Ob, Wprojt, bproj, out);
}

// Round 3
// 331.125 us; speedup vs baseline: 5.7813x; 1.4427x over previous
//
#include <hip/hip_runtime.h>
#include <math.h>

typedef __bf16 bf16x8 __attribute__((ext_vector_type(8)));
typedef float f32x4 __attribute__((ext_vector_type(4)));
typedef unsigned short u16;
typedef unsigned short u16x8 __attribute__((ext_vector_type(8)));
typedef unsigned short u16x4 __attribute__((ext_vector_type(4)));

#define BATCH 4
#define SEQ   2048
#define EMBD  1024
#define NHEAD 16
#define HDIM  64
#define MROWS 8192
#define QKVN  3072

__device__ __forceinline__ u16 f2bf(float f) {
    union { float f; unsigned u; } cv; cv.f = f;
    unsigned u = cv.u;
    return (u16)((u + 0x7FFFu + ((u >> 16) & 1u)) >> 16);
}

__device__ __forceinline__ void glds16(const void* g, void* l) {
    __builtin_amdgcn_global_load_lds(
        (const __attribute__((address_space(1))) unsigned int*)(g),
        (__attribute__((address_space(3))) unsigned int*)(l), 16, 0, 0);
}

// ---------------------------------------------------------------------------
__global__ __launch_bounds__(256)
void convert_f32_bf16(const float* __restrict__ in, u16* __restrict__ out, int n4) {
    int i = blockIdx.x * 256 + threadIdx.x;
    if (i < n4) {
        float4 v = ((const float4*)in)[i];
        u16x4 o = { f2bf(v.x), f2bf(v.y), f2bf(v.z), f2bf(v.w) };
        ((u16x4*)out)[i] = o;
    }
}

// ---------------------------------------------------------------------------
__global__ __launch_bounds__(256)
void transpose_convert(const float* __restrict__ W, u16* __restrict__ Wt, int K, int N) {
    __shared__ u16 T[64][68];
    const int tx = threadIdx.x & 15, ty = threadIdx.x >> 4;
    const int n0 = blockIdx.x * 64, k0 = blockIdx.y * 64;
#pragma unroll
    for (int r = 0; r < 4; r++) {
        int k = k0 + ty + r * 16;
        float4 w = *(const float4*)&W[(size_t)k * N + n0 + tx * 4];
        T[tx * 4 + 0][ty + r * 16] = f2bf(w.x);
        T[tx * 4 + 1][ty + r * 16] = f2bf(w.y);
        T[tx * 4 + 2][ty + r * 16] = f2bf(w.z);
        T[tx * 4 + 3][ty + r * 16] = f2bf(w.w);
    }
    __syncthreads();
#pragma unroll
    for (int r = 0; r < 4; r++) {
        int nl = ty + r * 16;
        u16x4 v = { T[nl][tx * 4 + 0], T[nl][tx * 4 + 1],
                    T[nl][tx * 4 + 2], T[nl][tx * 4 + 3] };
        *(u16x4*)&Wt[(size_t)(n0 + nl) * K + k0 + tx * 4] = v;
    }
}

// ---------------------------------------------------------------------------
// RoPE LUT: cos/sin[l][p], p = dh/2 in 0..31
// ---------------------------------------------------------------------------
__global__ __launch_bounds__(256)
void rope_prep(float* __restrict__ C, float* __restrict__ S) {
    int i = blockIdx.x * 256 + threadIdx.x;   // 65536
    int l = i >> 5, p = i & 31;
    float invf = powf(10000.0f, -(float)(2 * p) * (1.0f / 64.0f));
    float sv, cv;
    sincosf((float)l * invf, &sv, &cv);
    C[i] = cv; S[i] = sv;
}

// ---------------------------------------------------------------------------
// mask prep: bias (0 / -1e30) per key + per-128-tile all-ones flag
// ---------------------------------------------------------------------------
__global__ __launch_bounds__(128)
void mask_prep(const int* __restrict__ amask, float* __restrict__ mb, int* __restrict__ flags) {
    __shared__ int ok[2];
    int bid = blockIdx.x;                 // 64 = b*16 + kt
    int tid = threadIdx.x;
    int b = bid >> 4, kt = bid & 15;
    int idx = b * SEQ + kt * 128 + tid;
    int mv = amask[idx];
    mb[idx] = mv ? 0.0f : -1e30f;
    unsigned long long bal = __ballot(mv != 0);
    if ((tid & 63) == 0) ok[tid >> 6] = (bal == 0xFFFFFFFFFFFFFFFFull);
    __syncthreads();
    if (tid == 0) flags[bid] = ok[0] & ok[1];
}

// ---------------------------------------------------------------------------
// qkv GEMM + bias + RoPE(LUT) + scatter [B,H,L,Dh] bf16 (0.125 folded into Q)
// ---------------------------------------------------------------------------
__global__ __launch_bounds__(256)
void qkv_gemm(const u16* __restrict__ A, const u16* __restrict__ Bt,
              const float* __restrict__ bias,
              const float* __restrict__ Ct, const float* __restrict__ St,
              u16* __restrict__ Qo, u16* __restrict__ Ko, u16* __restrict__ Vo) {
    __shared__ u16 As[128 * 32];
    __shared__ u16 Bs[128 * 32];
    const int tid = threadIdx.x;
    const int wv = tid >> 6, ln = tid & 63;
    const int quad = ln >> 4, l16 = ln & 15;
    const int m0 = blockIdx.y * 128, n0 = blockIdx.x * 128;
    const int wm = wv >> 1, wn = wv & 1;

    f32x4 acc[4][4] = {};
    for (int k0 = 0; k0 < EMBD; k0 += 32) {
#pragma unroll
        for (int p = 0; p < 2; p++) {
            int slot = p * 256 + tid;
            int row = slot >> 2, ch = slot & 3;
            glds16(A  + (size_t)(m0 + row) * EMBD + k0 + ch * 8, As + (p * 256 + wv * 64) * 8);
            glds16(Bt + (size_t)(n0 + row) * EMBD + k0 + ch * 8, Bs + (p * 256 + wv * 64) * 8);
        }
        __syncthreads();
        bf16x8 af[4], bfr[4];
#pragma unroll
        for (int i = 0; i < 4; i++) af[i]  = *(const bf16x8*)&As[(wm * 64 + i * 16 + l16) * 32 + quad * 8];
#pragma unroll
        for (int j = 0; j < 4; j++) bfr[j] = *(const bf16x8*)&Bs[(wn * 64 + j * 16 + l16) * 32 + quad * 8];
#pragma unroll
        for (int i = 0; i < 4; i++)
#pragma unroll
            for (int j = 0; j < 4; j++)
                acc[i][j] = __builtin_amdgcn_mfma_f32_16x16x32_bf16(af[i], bfr[j], acc[i][j], 0, 0, 0);
        __syncthreads();
    }

    const int sec = n0 >> 10;
    if (sec == 2) {
#pragma unroll
        for (int i = 0; i < 4; i++)
#pragma unroll
            for (int r = 0; r < 4; r++) {
                int m = m0 + wm * 64 + i * 16 + quad * 4 + r;
                int b = m >> 11, l = m & 2047;
#pragma unroll
                for (int j = 0; j < 4; j++) {
                    int n = n0 + wn * 64 + j * 16 + l16;
                    int dcol = n & 1023;
                    int h = dcol >> 6, dh = dcol & 63;
                    float v = acc[i][j][r] + bias[n];
                    Vo[(((size_t)b * NHEAD + h) * SEQ + l) * HDIM + dh] = f2bf(v);
                }
            }
    } else {
        u16* O = (sec == 0) ? Qo : Ko;
        const float qs = (sec == 0) ? 0.125f : 1.0f;
#pragma unroll
        for (int i = 0; i < 4; i++)
#pragma unroll
            for (int r = 0; r < 4; r++) {
                int m = m0 + wm * 64 + i * 16 + quad * 4 + r;
                int b = m >> 11, l = m & 2047;
#pragma unroll
                for (int j = 0; j < 4; j++) {
                    int n = n0 + wn * 64 + j * 16 + l16;
                    int h = (n & 1023) >> 6, dh = n & 63;
                    int p = (n & 63) >> 1;
                    float v = acc[i][j][r] + bias[n];
                    float pv = __shfl_xor(v, 1, 64);
                    float cv = Ct[l * 32 + p], sv = St[l * 32 + p];
                    float o = (l16 & 1) ? (pv * sv + v * cv) : (v * cv - pv * sv);
                    O[(((size_t)b * NHEAD + h) * SEQ + l) * HDIM + dh] = f2bf(o * qs);
                }
            }
    }
}

// ---------------------------------------------------------------------------
// V [bh][l][dh] -> Vt [bh][dh][l]
// ---------------------------------------------------------------------------
__global__ __launch_bounds__(256)
void transpose_v(const u16* __restrict__ Vo, u16* __restrict__ Vt) {
    __shared__ u16 T[64][72];
    const int bh = blockIdx.y;
    const int l0 = blockIdx.x * 64;
    const int tx = threadIdx.x & 15, ty = threadIdx.x >> 4;
#pragma unroll
    for (int rr = 0; rr < 4; rr++) {
        int l = ty + rr * 16;
        u16x4 v = *(const u16x4*)&Vo[((size_t)bh * SEQ + l0 + l) * HDIM + tx * 4];
        T[l][tx * 4 + 0] = v.x; T[l][tx * 4 + 1] = v.y;
        T[l][tx * 4 + 2] = v.z; T[l][tx * 4 + 3] = v.w;
    }
    __syncthreads();
#pragma unroll
    for (int rr = 0; rr < 4; rr++) {
        int dh = ty + rr * 16;
        u16x4 w = { T[tx * 4 + 0][dh], T[tx * 4 + 1][dh],
                    T[tx * 4 + 2][dh], T[tx * 4 + 3][dh] };
        *(u16x4*)&Vt[((size_t)bh * HDIM + dh) * SEQ + l0 + tx * 4] = w;
    }
}

// ---------------------------------------------------------------------------
// Flash attention in transposed space: S^T = K Q^T, O^T = V^T P^T.
// 512 blocks; block = 4 waves x 32q; q-tile pair (15-slot, slot) = 17 iters.
// LDS 32KB (K + V^T swizzled). P^T via bpermute (no LDS round-trip).
// ---------------------------------------------------------------------------
__global__ __launch_bounds__(256)
void attn_mfma2(const u16* __restrict__ Qb, const u16* __restrict__ Kb,
                const u16* __restrict__ Vt, const float* __restrict__ mb,
                const int* __restrict__ flags, u16* __restrict__ Ot) {
    __shared__ u16 SM[16384];             // 32 KB
    u16* Ks = SM;                          // [128 key][64 dh] swizzled 16B chunks
    u16* Vs = SM + 8192;                   // [64 dh][128 key] swizzled 16B chunks
    const int tid = threadIdx.x;
    const int wv = tid >> 6, ln = tid & 63;
    const int quad = ln >> 4, l16 = ln & 15;
    const int slotb = blockIdx.x >> 6;     // 0..7
    const int bh = blockIdx.x & 63;
    const int b = bh >> 4, h = bh & 15;
    const u16* Qg = Qb + (size_t)bh * SEQ * HDIM;
    const u16* Kg = Kb + (size_t)bh * SEQ * HDIM;
    const u16* Vg = Vt + (size_t)bh * HDIM * SEQ;
    const unsigned selp = (quad >= 2) ? 0x07060302u : 0x05040100u;
    const int srcA = ((quad & 1) * 2) * 16 + l16;
    const int srcB = srcA + 16;
    const int sw = l16 & 7;

    for (int phase = 0; phase < 2; phase++) {
        const int qt = (phase == 0) ? (15 - slotb) : slotb;
        const int q0w = qt * 128 + wv * 32;
        bf16x8 Qf[2][2];
#pragma unroll
        for (int nq = 0; nq < 2; nq++)
#pragma unroll
            for (int kd = 0; kd < 2; kd++)
                Qf[nq][kd] = *(const bf16x8*)&Qg[(size_t)(q0w + nq * 16 + l16) * HDIM + kd * 32 + quad * 8];

        f32x4 o[4][2] = {};
        float mrun[2] = { -1e30f, -1e30f }, lrun[2] = { 0.f, 0.f };

        for (int kt = 0; kt <= qt; kt++) {
            const int kbase = kt * 128;
            // --- stage K and V^T (XOR-swizzled 16B chunks) ---
#pragma unroll
            for (int p = 0; p < 4; p++) {
                int s4 = p * 256 + tid;
                int key = s4 >> 3, cch = s4 & 7;
                u16x8 kv = *(const u16x8*)&Kg[(size_t)(kbase + key) * HDIM + cch * 8];
                *(u16x8*)&Ks[key * 64 + ((cch ^ (key & 7)) * 8)] = kv;
                int dh = s4 >> 4, kch = s4 & 15;
                u16x8 vv = *(const u16x8*)&Vg[(size_t)dh * SEQ + kbase + kch * 8];
                *(u16x8*)&Vs[dh * 128 + ((kch ^ (dh & 7)) * 8)] = vv;
            }
            __syncthreads();

            // --- S^T = K Q^T : per wave 128 keys x 32 q ---
            f32x4 s[8][2];
#pragma unroll
            for (int mi = 0; mi < 8; mi++) {
                const u16* kr = &Ks[(mi * 16 + l16) * 64];
                bf16x8 a0 = *(const bf16x8*)&kr[(quad ^ sw) * 8];
                bf16x8 a1 = *(const bf16x8*)&kr[((4 + quad) ^ sw) * 8];
                f32x4 z = {};
                s[mi][0] = __builtin_amdgcn_mfma_f32_16x16x32_bf16(a0, Qf[0][0], z, 0, 0, 0);
                s[mi][0] = __builtin_amdgcn_mfma_f32_16x16x32_bf16(a1, Qf[0][1], s[mi][0], 0, 0, 0);
                s[mi][1] = __builtin_amdgcn_mfma_f32_16x16x32_bf16(a0, Qf[1][0], z, 0, 0, 0);
                s[mi][1] = __builtin_amdgcn_mfma_f32_16x16x32_bf16(a1, Qf[1][1], s[mi][1], 0, 0, 0);
            }

            if (kt == qt) {   // causal mask on diagonal tile only
#pragma unroll
                for (int mi = 0; mi < 8; mi++)
#pragma unroll
                    for (int nq = 0; nq < 2; nq++) {
                        int qloc = wv * 32 + nq * 16 + l16;
#pragma unroll
                        for (int r = 0; r < 4; r++)
                            if (mi * 16 + quad * 4 + r > qloc) s[mi][nq][r] = -1e30f;
                    }
            }
            if (!flags[b * 16 + kt]) {   // cold path: key-mask bias
#pragma unroll
                for (int mi = 0; mi < 8; mi++)
#pragma unroll
                    for (int r = 0; r < 4; r++) {
                        float bias = mb[b * SEQ + kbase + mi * 16 + quad * 4 + r];
                        s[mi][0][r] += bias; s[mi][1][r] += bias;
                    }
            }

            // --- online softmax (row q = lane column; 2 shfl per nq) ---
#pragma unroll
            for (int nq = 0; nq < 2; nq++) {
                float rm = -1e30f;
#pragma unroll
                for (int mi = 0; mi < 8; mi++)
#pragma unroll
                    for (int r = 0; r < 4; r++) rm = fmaxf(rm, s[mi][nq][r]);
                rm = fmaxf(rm, __shfl_xor(rm, 16, 64));
                rm = fmaxf(rm, __shfl_xor(rm, 32, 64));
                float mnew = fmaxf(mrun[nq], rm);
                float al = __expf(mrun[nq] - mnew);
                mrun[nq] = mnew;
                float rs = 0.f;
#pragma unroll
                for (int mi = 0; mi < 8; mi++)
#pragma unroll
                    for (int r = 0; r < 4; r++) {
                        float pe = __expf(s[mi][nq][r] - mnew);
                        s[mi][nq][r] = pe;
                        rs += pe;
                    }
                rs += __shfl_xor(rs, 16, 64);
                rs += __shfl_xor(rs, 32, 64);
                lrun[nq] = lrun[nq] * al + rs;
#pragma unroll
                for (int md = 0; md < 4; md++)
#pragma unroll
                    for (int r = 0; r < 4; r++) o[md][nq][r] *= al;
            }

            // --- O^T += V^T P^T; P^T B-frags built via bpermute + v_perm ---
#pragma unroll
            for (int kc = 0; kc < 4; kc++) {
                union { unsigned u[4]; bf16x8 v; } pf[2];
#pragma unroll
                for (int nq = 0; nq < 2; nq++) {
                    unsigned fA[4], fB[4];
#pragma unroll
                    for (int r = 0; r < 4; r++) {
                        unsigned lo = __float_as_uint(s[2 * kc][nq][r]);
                        unsigned hi = __float_as_uint(s[2 * kc + 1][nq][r]);
                        // truncating bf16 pack: [bf16(lo) | bf16(hi)<<16]
                        unsigned pk = __builtin_amdgcn_perm(hi, lo, 0x07060302u);
                        fA[r] = (unsigned)__shfl((int)pk, srcA, 64);
                        fB[r] = (unsigned)__shfl((int)pk, srcB, 64);
                    }
                    pf[nq].u[0] = __builtin_amdgcn_perm(fA[1], fA[0], selp);
                    pf[nq].u[1] = __builtin_amdgcn_perm(fA[3], fA[2], selp);
                    pf[nq].u[2] = __builtin_amdgcn_perm(fB[1], fB[0], selp);
                    pf[nq].u[3] = __builtin_amdgcn_perm(fB[3], fB[2], selp);
                }
#pragma unroll
                for (int md = 0; md < 4; md++) {
                    bf16x8 vf = *(const bf16x8*)&Vs[(md * 16 + l16) * 128 + (((kc * 4 + quad) ^ sw) * 8)];
                    o[md][0] = __builtin_amdgcn_mfma_f32_16x16x32_bf16(vf, pf[0].v, o[md][0], 0, 0, 0);
                    o[md][1] = __builtin_amdgcn_mfma_f32_16x16x32_bf16(vf, pf[1].v, o[md][1], 0, 0, 0);
                }
            }
            __syncthreads();
        }

        // --- epilogue: normalize, transpose via LDS, coalesced store ---
        u16* Osh = SM + wv * 2176;   // [32 q][68 dh]
        float invl0 = 1.0f / lrun[0], invl1 = 1.0f / lrun[1];
#pragma unroll
        for (int md = 0; md < 4; md++)
#pragma unroll
            for (int nq = 0; nq < 2; nq++) {
                float inv = nq ? invl1 : invl0;
#pragma unroll
                for (int r = 0; r < 4; r++)
                    Osh[(nq * 16 + l16) * 68 + md * 16 + quad * 4 + r] = f2bf(o[md][nq][r] * inv);
            }
        __syncthreads();
        {
            int qrow = ln >> 1, hf = ln & 1;
            size_t gbase = ((size_t)bh * SEQ + qt * 128 + wv * 32 + qrow) * HDIM + hf * 32;
#pragma unroll
            for (int c = 0; c < 4; c++) {
                u16x8 vv = *(const u16x8*)&Osh[qrow * 68 + hf * 32 + c * 8];
                *(u16x8*)&Ot[gbase + c * 8] = vv;
            }
        }
        __syncthreads();
    }
}

// ---------------------------------------------------------------------------
// out = Ot @ Wprojt^T + b (fp32). A is [bh][l][64] -> logical [B*L][1024].
// ---------------------------------------------------------------------------
__global__ __launch_bounds__(256)
void proj_gemm(const u16* __restrict__ A, const u16* __restrict__ Bt,
               const float* __restrict__ bias, float* __restrict__ out) {
    __shared__ u16 As[128 * 32];
    __shared__ u16 Bs[128 * 32];
    const int tid = threadIdx.x;
    const int wv = tid >> 6, ln = tid & 63;
    const int quad = ln >> 4, l16 = ln & 15;
    const int m0 = blockIdx.y * 128, n0 = blockIdx.x * 128;
    const int wm = wv >> 1, wn = wv & 1;

    f32x4 acc[4][4] = {};
    for (int k0 = 0; k0 < EMBD; k0 += 32) {
#pragma unroll
        for (int p = 0; p < 2; p++) {
            int slot = p * 256 + tid;
            int row = slot >> 2, ch = slot & 3;
            int m = m0 + row;
            int bb = m >> 11, l = m & 2047;
            int hh = k0 >> 6;
            glds16(A + (((size_t)(bb * 16 + hh) * SEQ + l) * HDIM) + (k0 & 63) + ch * 8,
                   As + (p * 256 + wv * 64) * 8);
            glds16(Bt + (size_t)(n0 + row) * EMBD + k0 + ch * 8, Bs + (p * 256 + wv * 64) * 8);
        }
        __syncthreads();
        bf16x8 af[4], bfr[4];
#pragma unroll
        for (int i = 0; i < 4; i++) af[i]  = *(const bf16x8*)&As[(wm * 64 + i * 16 + l16) * 32 + quad * 8];
#pragma unroll
        for (int j = 0; j < 4; j++) bfr[j] = *(const bf16x8*)&Bs[(wn * 64 + j * 16 + l16) * 32 + quad * 8];
#pragma unroll
        for (int i = 0; i < 4; i++)
#pragma unroll
            for (int j = 0; j < 4; j++)
                acc[i][j] = __builtin_amdgcn_mfma_f32_16x16x32_bf16(af[i], bfr[j], acc[i][j], 0, 0, 0);
        __syncthreads();
    }
#pragma unroll
    for (int i = 0; i < 4; i++)
#pragma unroll
        for (int r = 0; r < 4; r++) {
            int m = m0 + wm * 64 + i * 16 + quad * 4 + r;
#pragma unroll
            for (int j = 0; j < 4; j++) {
                int n = n0 + wn * 64 + j * 16 + l16;
                out[(size_t)m * EMBD + n] = acc[i][j][r] + bias[n];
            }
        }
}

// ---------------------------------------------------------------------------
extern "C" void kernel_launch(void* const* d_in, const int* in_sizes, int n_in,
                              void* d_out, int out_size, void* d_ws, size_t ws_size,
                              hipStream_t stream)
{
    const float* x     = (const float*)d_in[0];
    const float* Wqkv  = (const float*)d_in[1];
    const float* bqkv  = (const float*)d_in[2];
    const float* Wproj = (const float*)d_in[3];
    const float* bproj = (const float*)d_in[4];
    const int*   amask = (const int*)d_in[5];
    float* out = (float*)d_out;

    char* ws = (char*)d_ws;
    u16*   Xb     = (u16*)(ws);                   // 16.78 MB (aliased by Ot later)
    u16*   Ot     = (u16*)(ws);                   // written after Xb is dead
    u16*   Wqkvt  = (u16*)(ws + 16777216);        //  6.29 MB
    u16*   Wprojt = (u16*)(ws + 23068672);        //  2.10 MB
    u16*   Qb     = (u16*)(ws + 25165824);        // 16.78 MB [bh][l][dh]
    u16*   Kb     = (u16*)(ws + 41943040);        // 16.78 MB
    u16*   Vb     = (u16*)(ws + 58720256);        // 16.78 MB [bh][l][dh]
    u16*   Vtp    = (u16*)(ws + 75497472);        // 16.78 MB [bh][dh][l]
    float* ropeC  = (float*)(ws + 92274688);      // 256 KB
    float* ropeS  = (float*)(ws + 92536832);      // 256 KB
    float* mbias  = (float*)(ws + 92798976);      // 32 KB
    int*   flags  = (int*)(ws + 92831744);        // 256 B

    convert_f32_bf16<<<8192, 256, 0, stream>>>(x, Xb, MROWS * EMBD / 4);
    transpose_convert<<<dim3(48, 16), 256, 0, stream>>>(Wqkv, Wqkvt, EMBD, QKVN);
    transpose_convert<<<dim3(16, 16), 256, 0, stream>>>(Wproj, Wprojt, EMBD, EMBD);
    rope_prep<<<256, 256, 0, stream>>>(ropeC, ropeS);
    mask_prep<<<64, 128, 0, stream>>>(amask, mbias, flags);
    qkv_gemm<<<dim3(QKVN / 128, MROWS / 128), 256, 0, stream>>>(
        Xb, Wqkvt, bqkv, ropeC, ropeS, Qb, Kb, Vb);
    transpose_v<<<dim3(32, 64), 256, 0, stream>>>(Vb, Vtp);
    attn_mfma2<<<512, 256, 0, stream>>>(Qb, Kb, Vtp, mbias, flags, Ot);
    proj_gemm<<<dim3(EMBD / 128, MROWS / 128), 256, 0, stream>>>(Ot, Wprojt, bproj, out);
}

// Round 4
// 321.520 us; speedup vs baseline: 5.9540x; 1.0299x over previous
//
#include <hip/hip_runtime.h>
#include <math.h>

typedef __bf16 bf16x8 __attribute__((ext_vector_type(8)));
typedef float f32x4 __attribute__((ext_vector_type(4)));
typedef unsigned short u16;
typedef unsigned short u16x8 __attribute__((ext_vector_type(8)));
typedef unsigned short u16x4 __attribute__((ext_vector_type(4)));

#define BATCH 4
#define SEQ   2048
#define EMBD  1024
#define NHEAD 16
#define HDIM  64
#define MROWS 8192
#define QKVN  3072

__device__ __forceinline__ u16 f2bf(float f) {
    union { float f; unsigned u; } cv; cv.f = f;
    unsigned u = cv.u;
    return (u16)((u + 0x7FFFu + ((u >> 16) & 1u)) >> 16);
}

__device__ __forceinline__ void glds16(const void* g, void* l) {
    __builtin_amdgcn_global_load_lds(
        (const __attribute__((address_space(1))) unsigned int*)(g),
        (__attribute__((address_space(3))) unsigned int*)(l), 16, 0, 0);
}

// ---------------------------------------------------------------------------
// Fused prep: X convert | Wqkv^T | Wproj^T | RoPE LUT | mask bias+flags
// ---------------------------------------------------------------------------
__device__ __forceinline__ void transpose_body(const float* __restrict__ W,
                                               u16* __restrict__ Wt, int K, int N,
                                               int n0, int k0, u16 (*T)[68]) {
    const int tx = threadIdx.x & 15, ty = threadIdx.x >> 4;
#pragma unroll
    for (int r = 0; r < 4; r++) {
        int k = k0 + ty + r * 16;
        float4 w = *(const float4*)&W[(size_t)k * N + n0 + tx * 4];
        T[tx * 4 + 0][ty + r * 16] = f2bf(w.x);
        T[tx * 4 + 1][ty + r * 16] = f2bf(w.y);
        T[tx * 4 + 2][ty + r * 16] = f2bf(w.z);
        T[tx * 4 + 3][ty + r * 16] = f2bf(w.w);
    }
    __syncthreads();
#pragma unroll
    for (int r = 0; r < 4; r++) {
        int nl = ty + r * 16;
        u16x4 v = { T[nl][tx * 4 + 0], T[nl][tx * 4 + 1],
                    T[nl][tx * 4 + 2], T[nl][tx * 4 + 3] };
        *(u16x4*)&Wt[(size_t)(n0 + nl) * K + k0 + tx * 4] = v;
    }
}

__global__ __launch_bounds__(256)
void prep_kernel(const float* __restrict__ x, const float* __restrict__ Wqkv,
                 const float* __restrict__ Wproj, const int* __restrict__ amask,
                 u16* __restrict__ Xb, u16* __restrict__ Wqkvt, u16* __restrict__ Wprojt,
                 float* __restrict__ ropeC, float* __restrict__ ropeS,
                 float* __restrict__ mbias, int* __restrict__ flags) {
    __shared__ union { u16 T[64][68]; int ok[4]; } sm;
    const int bx = blockIdx.x, tid = threadIdx.x;
    if (bx < 8192) {
        int i = bx * 256 + tid;
        float4 v = ((const float4*)x)[i];
        u16x4 o = { f2bf(v.x), f2bf(v.y), f2bf(v.z), f2bf(v.w) };
        ((u16x4*)Xb)[i] = o;
    } else if (bx < 8960) {
        int bxx = bx - 8192;                         // 768 blocks: 48 x 16
        transpose_body(Wqkv, Wqkvt, EMBD, QKVN, (bxx % 48) * 64, (bxx / 48) * 64, sm.T);
    } else if (bx < 9216) {
        int bxx = bx - 8960;                         // 256 blocks: 16 x 16
        transpose_body(Wproj, Wprojt, EMBD, EMBD, (bxx & 15) * 64, (bxx >> 4) * 64, sm.T);
    } else if (bx < 9472) {
        int i = (bx - 9216) * 256 + tid;             // 65536
        int l = i >> 5, p = i & 31;
        float invf = powf(10000.0f, -(float)(2 * p) * (1.0f / 64.0f));
        float sv, cv;
        sincosf((float)l * invf, &sv, &cv);
        ropeC[i] = cv; ropeS[i] = sv;
    } else {
        int idx = (bx - 9472) * 256 + tid;           // 8192 keys
        int mv = amask[idx];
        mbias[idx] = mv ? 0.0f : -1e30f;
        unsigned long long bal = __ballot(mv != 0);
        int wv = tid >> 6;
        if ((tid & 63) == 0) sm.ok[wv] = (bal == 0xFFFFFFFFFFFFFFFFull);
        __syncthreads();
        if (tid == 0)   flags[idx >> 7] = sm.ok[0] & sm.ok[1];
        if (tid == 128) flags[idx >> 7] = sm.ok[2] & sm.ok[3];
    }
}

// ---------------------------------------------------------------------------
// qkv GEMM + bias + RoPE(LUT) + scatter [B,H,L,Dh] bf16.
// Q folded scale = 0.125 * log2(e) so attention softmax can use native exp2.
// ---------------------------------------------------------------------------
__global__ __launch_bounds__(256)
void qkv_gemm(const u16* __restrict__ A, const u16* __restrict__ Bt,
              const float* __restrict__ bias,
              const float* __restrict__ Ct, const float* __restrict__ St,
              u16* __restrict__ Qo, u16* __restrict__ Ko, u16* __restrict__ Vo) {
    __shared__ u16 As[128 * 32];
    __shared__ u16 Bs[128 * 32];
    const int tid = threadIdx.x;
    const int wv = tid >> 6, ln = tid & 63;
    const int quad = ln >> 4, l16 = ln & 15;
    const int m0 = blockIdx.y * 128, n0 = blockIdx.x * 128;
    const int wm = wv >> 1, wn = wv & 1;

    f32x4 acc[4][4] = {};
    for (int k0 = 0; k0 < EMBD; k0 += 32) {
#pragma unroll
        for (int p = 0; p < 2; p++) {
            int slot = p * 256 + tid;
            int row = slot >> 2, ch = slot & 3;
            glds16(A  + (size_t)(m0 + row) * EMBD + k0 + ch * 8, As + (p * 256 + wv * 64) * 8);
            glds16(Bt + (size_t)(n0 + row) * EMBD + k0 + ch * 8, Bs + (p * 256 + wv * 64) * 8);
        }
        __syncthreads();
        bf16x8 af[4], bfr[4];
#pragma unroll
        for (int i = 0; i < 4; i++) af[i]  = *(const bf16x8*)&As[(wm * 64 + i * 16 + l16) * 32 + quad * 8];
#pragma unroll
        for (int j = 0; j < 4; j++) bfr[j] = *(const bf16x8*)&Bs[(wn * 64 + j * 16 + l16) * 32 + quad * 8];
#pragma unroll
        for (int i = 0; i < 4; i++)
#pragma unroll
            for (int j = 0; j < 4; j++)
                acc[i][j] = __builtin_amdgcn_mfma_f32_16x16x32_bf16(af[i], bfr[j], acc[i][j], 0, 0, 0);
        __syncthreads();
    }

    const int sec = n0 >> 10;
    if (sec == 2) {
#pragma unroll
        for (int i = 0; i < 4; i++)
#pragma unroll
            for (int r = 0; r < 4; r++) {
                int m = m0 + wm * 64 + i * 16 + quad * 4 + r;
                int b = m >> 11, l = m & 2047;
#pragma unroll
                for (int j = 0; j < 4; j++) {
                    int n = n0 + wn * 64 + j * 16 + l16;
                    int dcol = n & 1023;
                    int h = dcol >> 6, dh = dcol & 63;
                    float v = acc[i][j][r] + bias[n];
                    Vo[(((size_t)b * NHEAD + h) * SEQ + l) * HDIM + dh] = f2bf(v);
                }
            }
    } else {
        u16* O = (sec == 0) ? Qo : Ko;
        const float qs = (sec == 0) ? 0.125f * 1.44269504f : 1.0f;
#pragma unroll
        for (int i = 0; i < 4; i++)
#pragma unroll
            for (int r = 0; r < 4; r++) {
                int m = m0 + wm * 64 + i * 16 + quad * 4 + r;
                int b = m >> 11, l = m & 2047;
#pragma unroll
                for (int j = 0; j < 4; j++) {
                    int n = n0 + wn * 64 + j * 16 + l16;
                    int h = (n & 1023) >> 6, dh = n & 63;
                    int p = (n & 63) >> 1;
                    float v = acc[i][j][r] + bias[n];
                    float pv = __shfl_xor(v, 1, 64);
                    float cv = Ct[l * 32 + p], sv = St[l * 32 + p];
                    float o = (l16 & 1) ? (pv * sv + v * cv) : (v * cv - pv * sv);
                    O[(((size_t)b * NHEAD + h) * SEQ + l) * HDIM + dh] = f2bf(o * qs);
                }
            }
    }
}

// ---------------------------------------------------------------------------
// V [bh][l][dh] -> Vt [bh][dh][l]
// ---------------------------------------------------------------------------
__global__ __launch_bounds__(256)
void transpose_v(const u16* __restrict__ Vo, u16* __restrict__ Vt) {
    __shared__ u16 T[64][72];
    const int bh = blockIdx.y;
    const int l0 = blockIdx.x * 64;
    const int tx = threadIdx.x & 15, ty = threadIdx.x >> 4;
#pragma unroll
    for (int rr = 0; rr < 4; rr++) {
        int l = ty + rr * 16;
        u16x4 v = *(const u16x4*)&Vo[((size_t)bh * SEQ + l0 + l) * HDIM + tx * 4];
        T[l][tx * 4 + 0] = v.x; T[l][tx * 4 + 1] = v.y;
        T[l][tx * 4 + 2] = v.z; T[l][tx * 4 + 3] = v.w;
    }
    __syncthreads();
#pragma unroll
    for (int rr = 0; rr < 4; rr++) {
        int dh = ty + rr * 16;
        u16x4 w = { T[tx * 4 + 0][dh], T[tx * 4 + 1][dh],
                    T[tx * 4 + 2][dh], T[tx * 4 + 3][dh] };
        *(u16x4*)&Vt[((size_t)bh * HDIM + dh) * SEQ + l0 + tx * 4] = w;
    }
}

// ---------------------------------------------------------------------------
// Flash attention, transposed space: S^T = K Q^T, O^T = V^T P^T.
// 1024 blocks (one 128-q tile each), heavy tiles dispatched first.
// ---------------------------------------------------------------------------
__global__ __launch_bounds__(256)
void attn_mfma3(const u16* __restrict__ Qb, const u16* __restrict__ Kb,
                const u16* __restrict__ Vt, const float* __restrict__ mb,
                const int* __restrict__ flags, u16* __restrict__ Ot) {
    __shared__ u16 SM[16384];              // 32 KB
    u16* Ks = SM;                           // [128 key][64 dh] swizzled 16B chunks
    u16* Vs = SM + 8192;                    // [64 dh][128 key] swizzled 16B chunks
    const int tid = threadIdx.x;
    const int wv = tid >> 6, ln = tid & 63;
    const int quad = ln >> 4, l16 = ln & 15;
    const int qt = 15 - (blockIdx.x >> 6);  // heavy q-tiles first
    const int bh = blockIdx.x & 63;
    const int b = bh >> 4;
    const u16* Qg = Qb + (size_t)bh * SEQ * HDIM;
    const u16* Kg = Kb + (size_t)bh * SEQ * HDIM;
    const u16* Vg = Vt + (size_t)bh * HDIM * SEQ;
    const unsigned selp = (quad >= 2) ? 0x07060302u : 0x05040100u;
    const int srcA = ((quad & 1) * 2) * 16 + l16;
    const int srcB = srcA + 16;
    const int sw = l16 & 7;

    const int q0w = qt * 128 + wv * 32;
    bf16x8 Qf[2][2];
#pragma unroll
    for (int nq = 0; nq < 2; nq++)
#pragma unroll
        for (int kd = 0; kd < 2; kd++)
            Qf[nq][kd] = *(const bf16x8*)&Qg[(size_t)(q0w + nq * 16 + l16) * HDIM + kd * 32 + quad * 8];

    f32x4 o[4][2] = {};
    float mrun[2] = { -1e30f, -1e30f }, lrun[2] = { 0.f, 0.f };

    for (int kt = 0; kt <= qt; kt++) {
        const int kbase = kt * 128;
#pragma unroll
        for (int p = 0; p < 4; p++) {
            int s4 = p * 256 + tid;
            int key = s4 >> 3, cch = s4 & 7;
            u16x8 kv = *(const u16x8*)&Kg[(size_t)(kbase + key) * HDIM + cch * 8];
            *(u16x8*)&Ks[key * 64 + ((cch ^ (key & 7)) * 8)] = kv;
            int dh = s4 >> 4, kch = s4 & 15;
            u16x8 vv = *(const u16x8*)&Vg[(size_t)dh * SEQ + kbase + kch * 8];
            *(u16x8*)&Vs[dh * 128 + ((kch ^ (dh & 7)) * 8)] = vv;
        }
        __syncthreads();

        // --- S^T = K Q^T : per wave 128 keys x 32 q ---
        f32x4 s[8][2];
#pragma unroll
        for (int mi = 0; mi < 8; mi++) {
            const u16* kr = &Ks[(mi * 16 + l16) * 64];
            bf16x8 a0 = *(const bf16x8*)&kr[(quad ^ sw) * 8];
            bf16x8 a1 = *(const bf16x8*)&kr[((4 + quad) ^ sw) * 8];
            f32x4 z = {};
            s[mi][0] = __builtin_amdgcn_mfma_f32_16x16x32_bf16(a0, Qf[0][0], z, 0, 0, 0);
            s[mi][0] = __builtin_amdgcn_mfma_f32_16x16x32_bf16(a1, Qf[0][1], s[mi][0], 0, 0, 0);
            s[mi][1] = __builtin_amdgcn_mfma_f32_16x16x32_bf16(a0, Qf[1][0], z, 0, 0, 0);
            s[mi][1] = __builtin_amdgcn_mfma_f32_16x16x32_bf16(a1, Qf[1][1], s[mi][1], 0, 0, 0);
        }

        if (kt == qt) {   // causal mask on diagonal tile only
#pragma unroll
            for (int mi = 0; mi < 8; mi++)
#pragma unroll
                for (int nq = 0; nq < 2; nq++) {
                    int qloc = wv * 32 + nq * 16 + l16;
#pragma unroll
                    for (int r = 0; r < 4; r++)
                        if (mi * 16 + quad * 4 + r > qloc) s[mi][nq][r] = -1e30f;
                }
        }
        if (!flags[b * 16 + kt]) {   // cold path: key-mask bias
#pragma unroll
            for (int mi = 0; mi < 8; mi++)
#pragma unroll
                for (int r = 0; r < 4; r++) {
                    float bias = mb[b * SEQ + kbase + mi * 16 + quad * 4 + r];
                    s[mi][0][r] += bias; s[mi][1][r] += bias;
                }
        }

        // --- online softmax in exp2 space (log2e pre-folded into Q) ---
#pragma unroll
        for (int nq = 0; nq < 2; nq++) {
            float rm = -1e30f;
#pragma unroll
            for (int mi = 0; mi < 8; mi++)
#pragma unroll
                for (int r = 0; r < 4; r++) rm = fmaxf(rm, s[mi][nq][r]);
            rm = fmaxf(rm, __shfl_xor(rm, 16, 64));
            rm = fmaxf(rm, __shfl_xor(rm, 32, 64));
            float mnew = fmaxf(mrun[nq], rm);
            float al = __builtin_amdgcn_exp2f(mrun[nq] - mnew);
            mrun[nq] = mnew;
            float rs = 0.f;
#pragma unroll
            for (int mi = 0; mi < 8; mi++)
#pragma unroll
                for (int r = 0; r < 4; r++) {
                    float pe = __builtin_amdgcn_exp2f(s[mi][nq][r] - mnew);
                    s[mi][nq][r] = pe;
                    rs += pe;
                }
            rs += __shfl_xor(rs, 16, 64);
            rs += __shfl_xor(rs, 32, 64);
            lrun[nq] = lrun[nq] * al + rs;
#pragma unroll
            for (int md = 0; md < 4; md++)
#pragma unroll
                for (int r = 0; r < 4; r++) o[md][nq][r] *= al;
        }

        // --- O^T += V^T P^T; P^T B-frags via bpermute + v_perm ---
#pragma unroll
        for (int kc = 0; kc < 4; kc++) {
            union { unsigned u[4]; bf16x8 v; } pf[2];
#pragma unroll
            for (int nq = 0; nq < 2; nq++) {
                unsigned fA[4], fB[4];
#pragma unroll
                for (int r = 0; r < 4; r++) {
                    unsigned lo = __float_as_uint(s[2 * kc][nq][r]);
                    unsigned hi = __float_as_uint(s[2 * kc + 1][nq][r]);
                    unsigned pk = __builtin_amdgcn_perm(hi, lo, 0x07060302u);
                    fA[r] = (unsigned)__shfl((int)pk, srcA, 64);
                    fB[r] = (unsigned)__shfl((int)pk, srcB, 64);
                }
                pf[nq].u[0] = __builtin_amdgcn_perm(fA[1], fA[0], selp);
                pf[nq].u[1] = __builtin_amdgcn_perm(fA[3], fA[2], selp);
                pf[nq].u[2] = __builtin_amdgcn_perm(fB[1], fB[0], selp);
                pf[nq].u[3] = __builtin_amdgcn_perm(fB[3], fB[2], selp);
            }
#pragma unroll
            for (int md = 0; md < 4; md++) {
                bf16x8 vf = *(const bf16x8*)&Vs[(md * 16 + l16) * 128 + (((kc * 4 + quad) ^ sw) * 8)];
                o[md][0] = __builtin_amdgcn_mfma_f32_16x16x32_bf16(vf, pf[0].v, o[md][0], 0, 0, 0);
                o[md][1] = __builtin_amdgcn_mfma_f32_16x16x32_bf16(vf, pf[1].v, o[md][1], 0, 0, 0);
            }
        }
        __syncthreads();
    }

    // --- epilogue: normalize, transpose via LDS, coalesced store ---
    u16* Osh = SM + wv * 2176;   // [32 q][68 dh]
    float invl0 = 1.0f / lrun[0], invl1 = 1.0f / lrun[1];
#pragma unroll
    for (int md = 0; md < 4; md++)
#pragma unroll
        for (int nq = 0; nq < 2; nq++) {
            float inv = nq ? invl1 : invl0;
#pragma unroll
            for (int r = 0; r < 4; r++)
                Osh[(nq * 16 + l16) * 68 + md * 16 + quad * 4 + r] = f2bf(o[md][nq][r] * inv);
        }
    __syncthreads();
    {
        int qrow = ln >> 1, hf = ln & 1;
        size_t gbase = ((size_t)bh * SEQ + qt * 128 + wv * 32 + qrow) * HDIM + hf * 32;
#pragma unroll
        for (int c = 0; c < 4; c++) {
            u16x8 vv = *(const u16x8*)&Osh[qrow * 68 + hf * 32 + c * 8];
            *(u16x8*)&Ot[gbase + c * 8] = vv;
        }
    }
}

// ---------------------------------------------------------------------------
// out = Ot @ Wprojt^T + b (fp32). A is [bh][l][64] -> logical [B*L][1024].
// ---------------------------------------------------------------------------
__global__ __launch_bounds__(256)
void proj_gemm(const u16* __restrict__ A, const u16* __restrict__ Bt,
               const float* __restrict__ bias, float* __restrict__ out) {
    __shared__ u16 As[128 * 32];
    __shared__ u16 Bs[128 * 32];
    const int tid = threadIdx.x;
    const int wv = tid >> 6, ln = tid & 63;
    const int quad = ln >> 4, l16 = ln & 15;
    const int m0 = blockIdx.y * 128, n0 = blockIdx.x * 128;
    const int wm = wv >> 1, wn = wv & 1;

    f32x4 acc[4][4] = {};
    for (int k0 = 0; k0 < EMBD; k0 += 32) {
#pragma unroll
        for (int p = 0; p < 2; p++) {
            int slot = p * 256 + tid;
            int row = slot >> 2, ch = slot & 3;
            int m = m0 + row;
            int bb = m >> 11, l = m & 2047;
            int hh = k0 >> 6;
            glds16(A + (((size_t)(bb * 16 + hh) * SEQ + l) * HDIM) + (k0 & 63) + ch * 8,
                   As + (p * 256 + wv * 64) * 8);
            glds16(Bt + (size_t)(n0 + row) * EMBD + k0 + ch * 8, Bs + (p * 256 + wv * 64) * 8);
        }
        __syncthreads();
        bf16x8 af[4], bfr[4];
#pragma unroll
        for (int i = 0; i < 4; i++) af[i]  = *(const bf16x8*)&As[(wm * 64 + i * 16 + l16) * 32 + quad * 8];
#pragma unroll
        for (int j = 0; j < 4; j++) bfr[j] = *(const bf16x8*)&Bs[(wn * 64 + j * 16 + l16) * 32 + quad * 8];
#pragma unroll
        for (int i = 0; i < 4; i++)
#pragma unroll
            for (int j = 0; j < 4; j++)
                acc[i][j] = __builtin_amdgcn_mfma_f32_16x16x32_bf16(af[i], bfr[j], acc[i][j], 0, 0, 0);
        __syncthreads();
    }
#pragma unroll
    for (int i = 0; i < 4; i++)
#pragma unroll
        for (int r = 0; r < 4; r++) {
            int m = m0 + wm * 64 + i * 16 + quad * 4 + r;
#pragma unroll
            for (int j = 0; j < 4; j++) {
                int n = n0 + wn * 64 + j * 16 + l16;
                out[(size_t)m * EMBD + n] = acc[i][j][r] + bias[n];
            }
        }
}

// ---------------------------------------------------------------------------
extern "C" void kernel_launch(void* const* d_in, const int* in_sizes, int n_in,
                              void* d_out, int out_size, void* d_ws, size_t ws_size,
                              hipStream_t stream)
{
    const float* x     = (const float*)d_in[0];
    const float* Wqkv  = (const float*)d_in[1];
    const float* bqkv  = (const float*)d_in[2];
    const float* Wproj = (const float*)d_in[3];
    const float* bproj = (const float*)d_in[4];
    const int*   amask = (const int*)d_in[5];
    float* out = (float*)d_out;

    char* ws = (char*)d_ws;
    u16*   Xb     = (u16*)(ws);                   // 16.78 MB (aliased by Ot later)
    u16*   Ot     = (u16*)(ws);                   // written after Xb is dead
    u16*   Wqkvt  = (u16*)(ws + 16777216);        //  6.29 MB
    u16*   Wprojt = (u16*)(ws + 23068672);        //  2.10 MB
    u16*   Qb     = (u16*)(ws + 25165824);        // 16.78 MB [bh][l][dh]
    u16*   Kb     = (u16*)(ws + 41943040);        // 16.78 MB
    u16*   Vb     = (u16*)(ws + 58720256);        // 16.78 MB [bh][l][dh]
    u16*   Vtp    = (u16*)(ws + 75497472);        // 16.78 MB [bh][dh][l]
    float* ropeC  = (float*)(ws + 92274688);      // 256 KB
    float* ropeS  = (float*)(ws + 92536832);      // 256 KB
    float* mbias  = (float*)(ws + 92798976);      // 32 KB
    int*   flags  = (int*)(ws + 92831744);        // 256 B

    prep_kernel<<<9504, 256, 0, stream>>>(x, Wqkv, Wproj, amask,
                                          Xb, Wqkvt, Wprojt, ropeC, ropeS, mbias, flags);
    qkv_gemm<<<dim3(QKVN / 128, MROWS / 128), 256, 0, stream>>>(
        Xb, Wqkvt, bqkv, ropeC, ropeS, Qb, Kb, Vb);
    transpose_v<<<dim3(32, 64), 256, 0, stream>>>(Vb, Vtp);
    attn_mfma3<<<1024, 256, 0, stream>>>(Qb, Kb, Vtp, mbias, flags, Ot);
    proj_gemm<<<dim3(EMBD / 128, MROWS / 128), 256, 0, stream>>>(Ot, Wprojt, bproj, out);
}